// Round 1
// baseline (752.224 us; speedup 1.0000x reference)
//
#include <hip/hip_runtime.h>
#include <hip/hip_bf16.h>

#define SEQ 49
#define CH 768
#define NH 24
#define HD 32
#define NB 1024
#define NWIN 64
#define MTOT (NB*SEQ)      // 50176
#define K3 (3*CH)          // 2304

typedef __hip_bfloat16 bf16;
typedef __attribute__((ext_vector_type(8))) short short8;
typedef __attribute__((ext_vector_type(4))) float f32x4;

__device__ __forceinline__ void gload16(const void* g, void* l) {
  __builtin_amdgcn_global_load_lds((__attribute__((address_space(1))) void*)g,
                                   (__attribute__((address_space(3))) void*)l,
                                   16, 0, 0);
}

// ---------------- converters ----------------
__global__ void cvt_bf16(const float* __restrict__ in, bf16* __restrict__ o, int n4) {
  int i = blockIdx.x * blockDim.x + threadIdx.x;
  if (i >= n4) return;
  float4 v = ((const float4*)in)[i];
  union { bf16 b[4]; short4 s; } u;
  u.b[0] = __float2bfloat16(v.x);
  u.b[1] = __float2bfloat16(v.y);
  u.b[2] = __float2bfloat16(v.z);
  u.b[3] = __float2bfloat16(v.w);
  ((short4*)o)[i] = u.s;
}

// comb[s][h][mn] = rel_bias_table[rpi[mn]][h] + shift_mask[s][mn]
__global__ void build_comb(const float* __restrict__ table, const int* __restrict__ rpi,
                           const float* __restrict__ smask, float* __restrict__ comb) {
  int i = blockIdx.x * blockDim.x + threadIdx.x;
  if (i >= NWIN * NH * SEQ * SEQ) return;
  int mn = i % (SEQ * SEQ);
  int sh = i / (SEQ * SEQ);
  int h = sh % NH;
  int s = sh / NH;
  comb[i] = table[rpi[mn] * NH + h] + smask[s * SEQ * SEQ + mn];
}

// ---------------- kernel 1: QKV GEMM (m97 structure) ----------------
// C[M][2304] (bf16) = A[M][768] @ Bw[2304][768]^T + bias
__global__ __launch_bounds__(256) void qkv_gemm(
    const bf16* __restrict__ A, const bf16* __restrict__ Bw,
    const float* __restrict__ bias, bf16* __restrict__ C)
{
  __shared__ __align__(16) bf16 As[128 * 32];
  __shared__ __align__(16) bf16 Bs[128 * 32];
  const int tid = threadIdx.x;
  const int w = tid >> 6, l = tid & 63;
  const int lr = l & 15, lg = l >> 4;
  const int wm = w >> 1, wn = w & 1;
  const int bm = blockIdx.x, bn = blockIdx.y;

  const int srow = l >> 2, scol = (l & 3) << 3;
  const bf16* gA0 = A + ((size_t)(bm * 128 + 16 * w + srow)) * CH + scol;
  const bf16* gB0 = Bw + ((size_t)(bn * 128 + 16 * w + srow)) * CH + scol;
  bf16* lA0 = As + w * 512;          // wave-uniform, 1024 B per wave
  bf16* lA1 = As + 2048 + w * 512;
  bf16* lB0 = Bs + w * 512;
  bf16* lB1 = Bs + 2048 + w * 512;

  f32x4 acc[4][4];
  f32x4 zero4 = {0.f, 0.f, 0.f, 0.f};
#pragma unroll
  for (int i = 0; i < 4; i++)
#pragma unroll
    for (int j = 0; j < 4; j++) acc[i][j] = zero4;

  for (int kk = 0; kk < CH; kk += 32) {
    gload16(gA0 + kk, lA0);
    gload16(gA0 + 64 * CH + kk, lA1);
    gload16(gB0 + kk, lB0);
    gload16(gB0 + 64 * CH + kk, lB1);
    __syncthreads();
    short8 af[4], bfv[4];
#pragma unroll
    for (int mi = 0; mi < 4; mi++)
      af[mi] = *(const short8*)(As + (64 * wm + 16 * mi + lr) * 32 + 8 * lg);
#pragma unroll
    for (int nj = 0; nj < 4; nj++)
      bfv[nj] = *(const short8*)(Bs + (64 * wn + 16 * nj + lr) * 32 + 8 * lg);
#pragma unroll
    for (int mi = 0; mi < 4; mi++)
#pragma unroll
      for (int nj = 0; nj < 4; nj++)
        acc[mi][nj] = __builtin_amdgcn_mfma_f32_16x16x32_bf16(af[mi], bfv[nj], acc[mi][nj], 0, 0, 0);
    __syncthreads();
  }

  const int colbase = bn * 128 + 64 * wn;
  const int rowbase = bm * 128 + 64 * wm;
#pragma unroll
  for (int nj = 0; nj < 4; nj++) {
    int col = colbase + 16 * nj + lr;
    float bv = bias[col];
#pragma unroll
    for (int mi = 0; mi < 4; mi++) {
#pragma unroll
      for (int r = 0; r < 4; r++) {
        int row = rowbase + 16 * mi + 4 * lg + r;
        C[(size_t)row * K3 + col] = __float2bfloat16(acc[mi][nj][r] + bv);
      }
    }
  }
}

// ---------------- kernel 2: attention ----------------
// grid (1024, 6), 256 threads; wave w handles head blockIdx.y*4 + w
__global__ __launch_bounds__(256) void attn_kernel(
    const bf16* __restrict__ qkv, const float* __restrict__ comb,
    bf16* __restrict__ aout)
{
  __shared__ __align__(16) bf16 P[4][64 * 72];
  const int tid = threadIdx.x;
  const int w = tid >> 6, l = tid & 63;
  const int lr = l & 15, lg = l >> 4;
  const int b = blockIdx.x;
  const int h = blockIdx.y * 4 + w;
  const size_t rowb = (size_t)b * SEQ;
  const float scale = 0.17677669529663687f;  // 1/sqrt(32)
  f32x4 zero4 = {0.f, 0.f, 0.f, 0.f};

  // q,k fragments direct from global (16B contiguous along D)
  short8 qf[4], kf[4];
#pragma unroll
  for (int mt = 0; mt < 4; mt++) {
    size_t row = rowb + 16 * mt + lr;
    if (row > (size_t)(MTOT - 1)) row = MTOT - 1;
    qf[mt] = *(const short8*)(qkv + row * K3 + h * HD + 8 * lg);
  }
#pragma unroll
  for (int nt = 0; nt < 4; nt++) {
    size_t row = rowb + 16 * nt + lr;
    if (row > (size_t)(MTOT - 1)) row = MTOT - 1;
    kf[nt] = *(const short8*)(qkv + row * K3 + (NH + h) * HD + 8 * lg);
  }

  f32x4 s[4][4];
#pragma unroll
  for (int mt = 0; mt < 4; mt++)
#pragma unroll
    for (int nt = 0; nt < 4; nt++)
      s[mt][nt] = __builtin_amdgcn_mfma_f32_16x16x32_bf16(qf[mt], kf[nt], zero4, 0, 0, 0);

  // v fragments (B operand of PV): per-element, zero-pad n>=49 (no NaN from pads)
  const short* qkv_s = (const short*)qkv;
  short8 pb[2][2];
#pragma unroll
  for (int kt = 0; kt < 2; kt++)
#pragma unroll
    for (int dt = 0; dt < 2; dt++) {
      short8 t;
#pragma unroll
      for (int j = 0; j < 8; j++) {
        int n = 32 * kt + 8 * lg + j;
        short val = 0;
        if (n < SEQ) val = qkv_s[(rowb + n) * K3 + (2 * NH + h) * HD + 16 * dt + lr];
        t[j] = val;
      }
      pb[kt][dt] = t;
    }

  // scale + bias + mask, mask pads to -1e30
  const float* cb = comb + ((size_t)((b & (NWIN - 1)) * NH + h)) * (SEQ * SEQ);
#pragma unroll
  for (int mt = 0; mt < 4; mt++)
#pragma unroll
    for (int nt = 0; nt < 4; nt++)
#pragma unroll
      for (int r = 0; r < 4; r++) {
        int m = 16 * mt + 4 * lg + r, n = 16 * nt + lr;
        float v;
        if (m < SEQ && n < SEQ) v = s[mt][nt][r] * scale + cb[m * SEQ + n];
        else v = -1e30f;
        s[mt][nt][r] = v;
      }

  // softmax: row m lives in 16 lanes sharing lg; reduce via shfl_xor 1,2,4,8
  float mx[4][4];
#pragma unroll
  for (int mt = 0; mt < 4; mt++)
#pragma unroll
    for (int r = 0; r < 4; r++) {
      float m0 = fmaxf(fmaxf(s[mt][0][r], s[mt][1][r]), fmaxf(s[mt][2][r], s[mt][3][r]));
      m0 = fmaxf(m0, __shfl_xor(m0, 1, 64));
      m0 = fmaxf(m0, __shfl_xor(m0, 2, 64));
      m0 = fmaxf(m0, __shfl_xor(m0, 4, 64));
      m0 = fmaxf(m0, __shfl_xor(m0, 8, 64));
      mx[mt][r] = m0;
    }
  float inv[4][4];
#pragma unroll
  for (int mt = 0; mt < 4; mt++)
#pragma unroll
    for (int r = 0; r < 4; r++) {
      float t = 0.f;
#pragma unroll
      for (int nt = 0; nt < 4; nt++) {
        float e = __expf(s[mt][nt][r] - mx[mt][r]);
        s[mt][nt][r] = e;
        t += e;
      }
      t += __shfl_xor(t, 1, 64);
      t += __shfl_xor(t, 2, 64);
      t += __shfl_xor(t, 4, 64);
      t += __shfl_xor(t, 8, 64);
      inv[mt][r] = 1.0f / t;
    }

  // P to LDS (pitch 72 keeps b128 reads 16B-aligned, low conflicts)
#pragma unroll
  for (int mt = 0; mt < 4; mt++)
#pragma unroll
    for (int nt = 0; nt < 4; nt++)
#pragma unroll
      for (int r = 0; r < 4; r++)
        P[w][(16 * mt + 4 * lg + r) * 72 + 16 * nt + lr] =
            __float2bfloat16(s[mt][nt][r] * inv[mt][r]);

  // PV
  f32x4 o[4][2];
#pragma unroll
  for (int mt = 0; mt < 4; mt++) { o[mt][0] = zero4; o[mt][1] = zero4; }
#pragma unroll
  for (int kt = 0; kt < 2; kt++) {
    short8 pa[4];
#pragma unroll
    for (int mt = 0; mt < 4; mt++)
      pa[mt] = *(const short8*)(&P[w][(16 * mt + lr) * 72 + 32 * kt + 8 * lg]);
#pragma unroll
    for (int mt = 0; mt < 4; mt++)
#pragma unroll
      for (int dt = 0; dt < 2; dt++)
        o[mt][dt] = __builtin_amdgcn_mfma_f32_16x16x32_bf16(pa[mt], pb[kt][dt], o[mt][dt], 0, 0, 0);
  }

#pragma unroll
  for (int mt = 0; mt < 4; mt++)
#pragma unroll
    for (int dt = 0; dt < 2; dt++)
#pragma unroll
      for (int r = 0; r < 4; r++) {
        int m = 16 * mt + 4 * lg + r;
        if (m < SEQ)
          aout[(rowb + m) * CH + h * HD + 16 * dt + lr] = __float2bfloat16(o[mt][dt][r]);
      }
}

// ---------------- kernel 3: proj + bias + residual + LayerNorm ----------------
// 32 rows x full 768 cols per block; 512 threads (8 waves, wave w owns cols 96w..96w+95)
__global__ __launch_bounds__(512) void proj_ln(
    const bf16* __restrict__ Aat, const bf16* __restrict__ Wp,
    const float* __restrict__ bp, const float* __restrict__ x,
    const float* __restrict__ lgam, const float* __restrict__ lbet,
    float* __restrict__ out)
{
  __shared__ __align__(16) bf16 As[32 * 768];  // 48 KB, chunk-XOR swizzled
  __shared__ float part1[8][32];
  __shared__ float part2[8][32];
  __shared__ float mu_s[32], rs_s[32];
  const int tid = threadIdx.x;
  const int w = tid >> 6, l = tid & 63;
  const int lr = l & 15, lgp = l >> 4;
  const size_t row0 = (size_t)blockIdx.x * 32;

  // stage A (32x768 bf16) with inverse-swizzled global source, linear LDS dest
  const char* gbase = (const char*)Aat + row0 * CH * 2;
#pragma unroll
  for (int p = 0; p < 6; p++) {
    int o = p * 8192 + w * 1024 + l * 16;
    int r = o / 1536;
    int cch = (o - r * 1536) >> 4;
    int src = r * 1536 + ((cch ^ (r & 7)) << 4);
    gload16(gbase + src, (char*)As + p * 8192 + w * 1024);
  }
  __syncthreads();

  f32x4 zero4 = {0.f, 0.f, 0.f, 0.f};
  f32x4 acc[2][6];
#pragma unroll
  for (int i = 0; i < 2; i++)
#pragma unroll
    for (int j = 0; j < 6; j++) acc[i][j] = zero4;

  for (int ks = 0; ks < 24; ks++) {
    short8 af[2];
#pragma unroll
    for (int mt = 0; mt < 2; mt++) {
      int rrow = 16 * mt + lr;
      int cch = 4 * ks + lgp;
      int sw = cch ^ (rrow & 7);
      af[mt] = *(const short8*)((const char*)As + rrow * 1536 + (sw << 4));
    }
#pragma unroll
    for (int nj = 0; nj < 6; nj++) {
      short8 bfv = *(const short8*)(Wp + (size_t)(96 * w + 16 * nj + lr) * CH + 32 * ks + 8 * lgp);
#pragma unroll
      for (int mt = 0; mt < 2; mt++)
        acc[mt][nj] = __builtin_amdgcn_mfma_f32_16x16x32_bf16(af[mt], bfv, acc[mt][nj], 0, 0, 0);
    }
  }

  // epilogue: bias + residual, per-row partial stats
  float y[2][6][4];
  float s1[2][4], s2[2][4];
#pragma unroll
  for (int mt = 0; mt < 2; mt++)
#pragma unroll
    for (int r = 0; r < 4; r++) { s1[mt][r] = 0.f; s2[mt][r] = 0.f; }
#pragma unroll
  for (int mt = 0; mt < 2; mt++)
#pragma unroll
    for (int nj = 0; nj < 6; nj++)
#pragma unroll
      for (int r = 0; r < 4; r++) {
        int m = 16 * mt + 4 * lgp + r;
        int col = 96 * w + 16 * nj + lr;
        float v = acc[mt][nj][r] + bp[col] + x[(row0 + m) * CH + col];
        y[mt][nj][r] = v;
        s1[mt][r] += v;
        s2[mt][r] += v * v;
      }
#pragma unroll
  for (int mt = 0; mt < 2; mt++)
#pragma unroll
    for (int r = 0; r < 4; r++) {
      float a = s1[mt][r], bq = s2[mt][r];
      a += __shfl_xor(a, 1, 64);  bq += __shfl_xor(bq, 1, 64);
      a += __shfl_xor(a, 2, 64);  bq += __shfl_xor(bq, 2, 64);
      a += __shfl_xor(a, 4, 64);  bq += __shfl_xor(bq, 4, 64);
      a += __shfl_xor(a, 8, 64);  bq += __shfl_xor(bq, 8, 64);
      if (lr == 0) {
        int m = 16 * mt + 4 * lgp + r;
        part1[w][m] = a;
        part2[w][m] = bq;
      }
    }
  __syncthreads();
  if (tid < 32) {
    float a = 0.f, bq = 0.f;
#pragma unroll
    for (int i = 0; i < 8; i++) { a += part1[i][tid]; bq += part2[i][tid]; }
    float mu = a * (1.0f / 768.0f);
    float var = bq * (1.0f / 768.0f) - mu * mu;
    mu_s[tid] = mu;
    rs_s[tid] = rsqrtf(var + 1e-5f);
  }
  __syncthreads();
#pragma unroll
  for (int mt = 0; mt < 2; mt++)
#pragma unroll
    for (int nj = 0; nj < 6; nj++)
#pragma unroll
      for (int r = 0; r < 4; r++) {
        int m = 16 * mt + 4 * lgp + r;
        int col = 96 * w + 16 * nj + lr;
        out[(row0 + m) * CH + col] = (y[mt][nj][r] - mu_s[m]) * rs_s[m] * lgam[col] + lbet[col];
      }
}

// ---------------- launch ----------------
extern "C" void kernel_launch(void* const* d_in, const int* in_sizes, int n_in,
                              void* d_out, int out_size, void* d_ws, size_t ws_size,
                              hipStream_t stream) {
  (void)in_sizes; (void)n_in; (void)out_size; (void)ws_size;
  const float* x     = (const float*)d_in[0];
  const float* smask = (const float*)d_in[1];
  const float* wqkv  = (const float*)d_in[2];
  const float* bqkv  = (const float*)d_in[3];
  const float* wproj = (const float*)d_in[4];
  const float* bproj = (const float*)d_in[5];
  const float* table = (const float*)d_in[6];
  const float* lng   = (const float*)d_in[7];
  const float* lnb   = (const float*)d_in[8];
  const int*   rpi   = (const int*)d_in[9];
  float* out = (float*)d_out;

  char* ws = (char*)d_ws;
  bf16*  xb   = (bf16*)(ws);                      // 77,070,336 B
  bf16*  wqb  = (bf16*)(ws + 77070336);           //  3,538,944 B
  bf16*  wpb  = (bf16*)(ws + 80609280);           //  1,179,648 B
  float* comb = (float*)(ws + 81788928);          // 14,745,600 B
  bf16*  qkv  = (bf16*)(ws + 96534528);           // 231,211,008 B
  bf16*  aout = (bf16*)(ws + 327745536);          // 77,070,336 B -> ends 404,815,872

  cvt_bf16<<<37632, 256, 0, stream>>>(x, xb, 9633792);
  cvt_bf16<<<1728, 256, 0, stream>>>(wqkv, wqb, 442368);
  cvt_bf16<<<576, 256, 0, stream>>>(wproj, wpb, 147456);
  build_comb<<<14400, 256, 0, stream>>>(table, rpi, smask, comb);
  qkv_gemm<<<dim3(392, 18), 256, 0, stream>>>(xb, wqb, bqkv, qkv);
  attn_kernel<<<dim3(1024, 6), 256, 0, stream>>>(qkv, comb, aout);
  proj_ln<<<1568, 512, 0, stream>>>(aout, wpb, bproj, x, lng, lnb, out);
}

// Round 2
// 652.553 us; speedup vs baseline: 1.1527x; 1.1527x over previous
//
#include <hip/hip_runtime.h>
#include <hip/hip_bf16.h>

#define SEQ 49
#define CH 768
#define NH 24
#define HD 32
#define NB 1024
#define NWIN 64
#define MTOT (NB*SEQ)      // 50176
#define K3 (3*CH)          // 2304

typedef __hip_bfloat16 bf16;
typedef __attribute__((ext_vector_type(8))) short short8;
typedef __attribute__((ext_vector_type(4))) short short4v;
typedef __attribute__((ext_vector_type(4))) float f32x4;

__device__ __forceinline__ void gload16(const void* g, void* l) {
  __builtin_amdgcn_global_load_lds((__attribute__((address_space(1))) void*)g,
                                   (__attribute__((address_space(3))) void*)l,
                                   16, 0, 0);
}

__device__ __forceinline__ float bf2f(short s) {
  return __uint_as_float(((unsigned int)(unsigned short)s) << 16);
}

// ---------------- converters ----------------
__global__ void cvt_bf16(const float* __restrict__ in, bf16* __restrict__ o, int n4) {
  int i = blockIdx.x * blockDim.x + threadIdx.x;
  if (i >= n4) return;
  float4 v = ((const float4*)in)[i];
  union { bf16 b[4]; short4 s; } u;
  u.b[0] = __float2bfloat16(v.x);
  u.b[1] = __float2bfloat16(v.y);
  u.b[2] = __float2bfloat16(v.z);
  u.b[3] = __float2bfloat16(v.w);
  ((short4*)o)[i] = u.s;
}

// comb[s][h][mn] = rel_bias_table[rpi[mn]][h] + shift_mask[s][mn]
__global__ void build_comb(const float* __restrict__ table, const int* __restrict__ rpi,
                           const float* __restrict__ smask, float* __restrict__ comb) {
  int i = blockIdx.x * blockDim.x + threadIdx.x;
  if (i >= NWIN * NH * SEQ * SEQ) return;
  int mn = i % (SEQ * SEQ);
  int sh = i / (SEQ * SEQ);
  int h = sh % NH;
  int s = sh / NH;
  comb[i] = table[rpi[mn] * NH + h] + smask[s * SEQ * SEQ + mn];
}

// ---------------- kernel 1: QKV GEMM (m97 structure) ----------------
// C[M][2304] (bf16) = A[M][768] @ Bw[2304][768]^T + bias
__global__ __launch_bounds__(256) void qkv_gemm(
    const bf16* __restrict__ A, const bf16* __restrict__ Bw,
    const float* __restrict__ bias, bf16* __restrict__ C)
{
  __shared__ __align__(16) bf16 As[128 * 32];
  __shared__ __align__(16) bf16 Bs[128 * 32];
  const int tid = threadIdx.x;
  const int w = tid >> 6, l = tid & 63;
  const int lr = l & 15, lg = l >> 4;
  const int wm = w >> 1, wn = w & 1;
  const int bm = blockIdx.x, bn = blockIdx.y;

  const int srow = l >> 2, scol = (l & 3) << 3;
  const bf16* gA0 = A + ((size_t)(bm * 128 + 16 * w + srow)) * CH + scol;
  const bf16* gB0 = Bw + ((size_t)(bn * 128 + 16 * w + srow)) * CH + scol;
  bf16* lA0 = As + w * 512;          // wave-uniform, 1024 B per wave
  bf16* lA1 = As + 2048 + w * 512;
  bf16* lB0 = Bs + w * 512;
  bf16* lB1 = Bs + 2048 + w * 512;

  f32x4 acc[4][4];
  f32x4 zero4 = {0.f, 0.f, 0.f, 0.f};
#pragma unroll
  for (int i = 0; i < 4; i++)
#pragma unroll
    for (int j = 0; j < 4; j++) acc[i][j] = zero4;

  for (int kk = 0; kk < CH; kk += 32) {
    gload16(gA0 + kk, lA0);
    gload16(gA0 + 64 * CH + kk, lA1);
    gload16(gB0 + kk, lB0);
    gload16(gB0 + 64 * CH + kk, lB1);
    __syncthreads();
    short8 af[4], bfv[4];
#pragma unroll
    for (int mi = 0; mi < 4; mi++)
      af[mi] = *(const short8*)(As + (64 * wm + 16 * mi + lr) * 32 + 8 * lg);
#pragma unroll
    for (int nj = 0; nj < 4; nj++)
      bfv[nj] = *(const short8*)(Bs + (64 * wn + 16 * nj + lr) * 32 + 8 * lg);
#pragma unroll
    for (int mi = 0; mi < 4; mi++)
#pragma unroll
      for (int nj = 0; nj < 4; nj++)
        acc[mi][nj] = __builtin_amdgcn_mfma_f32_16x16x32_bf16(af[mi], bfv[nj], acc[mi][nj], 0, 0, 0);
    __syncthreads();
  }

  const int colbase = bn * 128 + 64 * wn;
  const int rowbase = bm * 128 + 64 * wm;
#pragma unroll
  for (int nj = 0; nj < 4; nj++) {
    int col = colbase + 16 * nj + lr;
    float bv = bias[col];
#pragma unroll
    for (int mi = 0; mi < 4; mi++) {
#pragma unroll
      for (int r = 0; r < 4; r++) {
        int row = rowbase + 16 * mi + 4 * lg + r;
        C[(size_t)row * K3 + col] = __float2bfloat16(acc[mi][nj][r] + bv);
      }
    }
  }
}

// ---------------- kernel 2: attention ----------------
// grid (1024, 6), 256 threads; wave w handles head blockIdx.y*4 + w
__global__ __launch_bounds__(256) void attn_kernel(
    const bf16* __restrict__ qkv, const float* __restrict__ comb,
    bf16* __restrict__ aout)
{
  __shared__ __align__(16) bf16 P[4][64 * 72];
  const int tid = threadIdx.x;
  const int w = tid >> 6, l = tid & 63;
  const int lr = l & 15, lg = l >> 4;
  const int b = blockIdx.x;
  const int h = blockIdx.y * 4 + w;
  const size_t rowb = (size_t)b * SEQ;
  const float scale = 0.17677669529663687f;  // 1/sqrt(32)
  f32x4 zero4 = {0.f, 0.f, 0.f, 0.f};

  short8 qf[4], kf[4];
#pragma unroll
  for (int mt = 0; mt < 4; mt++) {
    size_t row = rowb + 16 * mt + lr;
    if (row > (size_t)(MTOT - 1)) row = MTOT - 1;
    qf[mt] = *(const short8*)(qkv + row * K3 + h * HD + 8 * lg);
  }
#pragma unroll
  for (int nt = 0; nt < 4; nt++) {
    size_t row = rowb + 16 * nt + lr;
    if (row > (size_t)(MTOT - 1)) row = MTOT - 1;
    kf[nt] = *(const short8*)(qkv + row * K3 + (NH + h) * HD + 8 * lg);
  }

  f32x4 s[4][4];
#pragma unroll
  for (int mt = 0; mt < 4; mt++)
#pragma unroll
    for (int nt = 0; nt < 4; nt++)
      s[mt][nt] = __builtin_amdgcn_mfma_f32_16x16x32_bf16(qf[mt], kf[nt], zero4, 0, 0, 0);

  const short* qkv_s = (const short*)qkv;
  short8 pb[2][2];
#pragma unroll
  for (int kt = 0; kt < 2; kt++)
#pragma unroll
    for (int dt = 0; dt < 2; dt++) {
      short8 t;
#pragma unroll
      for (int j = 0; j < 8; j++) {
        int n = 32 * kt + 8 * lg + j;
        short val = 0;
        if (n < SEQ) val = qkv_s[(rowb + n) * K3 + (2 * NH + h) * HD + 16 * dt + lr];
        t[j] = val;
      }
      pb[kt][dt] = t;
    }

  const float* cb = comb + ((size_t)((b & (NWIN - 1)) * NH + h)) * (SEQ * SEQ);
#pragma unroll
  for (int mt = 0; mt < 4; mt++)
#pragma unroll
    for (int nt = 0; nt < 4; nt++)
#pragma unroll
      for (int r = 0; r < 4; r++) {
        int m = 16 * mt + 4 * lg + r, n = 16 * nt + lr;
        float v;
        if (m < SEQ && n < SEQ) v = s[mt][nt][r] * scale + cb[m * SEQ + n];
        else v = -1e30f;
        s[mt][nt][r] = v;
      }

  float mx[4][4];
#pragma unroll
  for (int mt = 0; mt < 4; mt++)
#pragma unroll
    for (int r = 0; r < 4; r++) {
      float m0 = fmaxf(fmaxf(s[mt][0][r], s[mt][1][r]), fmaxf(s[mt][2][r], s[mt][3][r]));
      m0 = fmaxf(m0, __shfl_xor(m0, 1, 64));
      m0 = fmaxf(m0, __shfl_xor(m0, 2, 64));
      m0 = fmaxf(m0, __shfl_xor(m0, 4, 64));
      m0 = fmaxf(m0, __shfl_xor(m0, 8, 64));
      mx[mt][r] = m0;
    }
  float inv[4][4];
#pragma unroll
  for (int mt = 0; mt < 4; mt++)
#pragma unroll
    for (int r = 0; r < 4; r++) {
      float t = 0.f;
#pragma unroll
      for (int nt = 0; nt < 4; nt++) {
        float e = __expf(s[mt][nt][r] - mx[mt][r]);
        s[mt][nt][r] = e;
        t += e;
      }
      t += __shfl_xor(t, 1, 64);
      t += __shfl_xor(t, 2, 64);
      t += __shfl_xor(t, 4, 64);
      t += __shfl_xor(t, 8, 64);
      inv[mt][r] = 1.0f / t;
    }

#pragma unroll
  for (int mt = 0; mt < 4; mt++)
#pragma unroll
    for (int nt = 0; nt < 4; nt++)
#pragma unroll
      for (int r = 0; r < 4; r++)
        P[w][(16 * mt + 4 * lg + r) * 72 + 16 * nt + lr] =
            __float2bfloat16(s[mt][nt][r] * inv[mt][r]);

  f32x4 o[4][2];
#pragma unroll
  for (int mt = 0; mt < 4; mt++) { o[mt][0] = zero4; o[mt][1] = zero4; }
#pragma unroll
  for (int kt = 0; kt < 2; kt++) {
    short8 pa[4];
#pragma unroll
    for (int mt = 0; mt < 4; mt++)
      pa[mt] = *(const short8*)(&P[w][(16 * mt + lr) * 72 + 32 * kt + 8 * lg]);
#pragma unroll
    for (int mt = 0; mt < 4; mt++)
#pragma unroll
      for (int dt = 0; dt < 2; dt++)
        o[mt][dt] = __builtin_amdgcn_mfma_f32_16x16x32_bf16(pa[mt], pb[kt][dt], o[mt][dt], 0, 0, 0);
  }

#pragma unroll
  for (int mt = 0; mt < 4; mt++)
#pragma unroll
    for (int dt = 0; dt < 2; dt++)
#pragma unroll
      for (int r = 0; r < 4; r++) {
        int m = 16 * mt + 4 * lg + r;
        if (m < SEQ)
          aout[(rowb + m) * CH + h * HD + 16 * dt + lr] = __float2bfloat16(o[mt][dt][r]);
      }
}

// ---------------- kernel 3: proj GEMM (m97 structure) + bias + residual ----------------
// Y[M][768] (bf16) = A[M][768] @ Wp[768][768]^T + bias + x
__global__ __launch_bounds__(256) void proj_gemm(
    const bf16* __restrict__ A, const bf16* __restrict__ Bw,
    const float* __restrict__ bias, const float* __restrict__ x,
    bf16* __restrict__ Y)
{
  __shared__ __align__(16) bf16 As[128 * 32];
  __shared__ __align__(16) bf16 Bs[128 * 32];
  const int tid = threadIdx.x;
  const int w = tid >> 6, l = tid & 63;
  const int lr = l & 15, lg = l >> 4;
  const int wm = w >> 1, wn = w & 1;
  const int bm = blockIdx.x, bn = blockIdx.y;

  const int srow = l >> 2, scol = (l & 3) << 3;
  const bf16* gA0 = A + ((size_t)(bm * 128 + 16 * w + srow)) * CH + scol;
  const bf16* gB0 = Bw + ((size_t)(bn * 128 + 16 * w + srow)) * CH + scol;
  bf16* lA0 = As + w * 512;
  bf16* lA1 = As + 2048 + w * 512;
  bf16* lB0 = Bs + w * 512;
  bf16* lB1 = Bs + 2048 + w * 512;

  f32x4 acc[4][4];
  f32x4 zero4 = {0.f, 0.f, 0.f, 0.f};
#pragma unroll
  for (int i = 0; i < 4; i++)
#pragma unroll
    for (int j = 0; j < 4; j++) acc[i][j] = zero4;

  for (int kk = 0; kk < CH; kk += 32) {
    gload16(gA0 + kk, lA0);
    gload16(gA0 + 64 * CH + kk, lA1);
    gload16(gB0 + kk, lB0);
    gload16(gB0 + 64 * CH + kk, lB1);
    __syncthreads();
    short8 af[4], bfv[4];
#pragma unroll
    for (int mi = 0; mi < 4; mi++)
      af[mi] = *(const short8*)(As + (64 * wm + 16 * mi + lr) * 32 + 8 * lg);
#pragma unroll
    for (int nj = 0; nj < 4; nj++)
      bfv[nj] = *(const short8*)(Bs + (64 * wn + 16 * nj + lr) * 32 + 8 * lg);
#pragma unroll
    for (int mi = 0; mi < 4; mi++)
#pragma unroll
      for (int nj = 0; nj < 4; nj++)
        acc[mi][nj] = __builtin_amdgcn_mfma_f32_16x16x32_bf16(af[mi], bfv[nj], acc[mi][nj], 0, 0, 0);
    __syncthreads();
  }

  const int colbase = bn * 128 + 64 * wn;
  const int rowbase = bm * 128 + 64 * wm;
#pragma unroll
  for (int nj = 0; nj < 4; nj++) {
    int col = colbase + 16 * nj + lr;
    float bv = bias[col];
#pragma unroll
    for (int mi = 0; mi < 4; mi++) {
#pragma unroll
      for (int r = 0; r < 4; r++) {
        size_t row = rowbase + 16 * mi + 4 * lg + r;
        float v = acc[mi][nj][r] + bv + x[row * CH + col];
        Y[row * CH + col] = __float2bfloat16(v);
      }
    }
  }
}

// ---------------- kernel 4: LayerNorm ----------------
// one row (768) per wave; 4 waves per block
__global__ __launch_bounds__(256) void ln_kernel(
    const bf16* __restrict__ Y, const float* __restrict__ g,
    const float* __restrict__ be, float* __restrict__ out)
{
  const int w = threadIdx.x >> 6, l = threadIdx.x & 63;
  const size_t r = (size_t)blockIdx.x * 4 + w;
  const bf16* yr = Y + r * CH;

  short8 a = *(const short8*)(yr + 8 * l);
  short4v b4 = *(const short4v*)(yr + 512 + 4 * l);
  float v[12];
#pragma unroll
  for (int j = 0; j < 8; j++) v[j] = bf2f(a[j]);
#pragma unroll
  for (int j = 0; j < 4; j++) v[8 + j] = bf2f(b4[j]);

  float s1 = 0.f, s2 = 0.f;
#pragma unroll
  for (int j = 0; j < 12; j++) { s1 += v[j]; s2 += v[j] * v[j]; }
#pragma unroll
  for (int m = 1; m <= 32; m <<= 1) {
    s1 += __shfl_xor(s1, m, 64);
    s2 += __shfl_xor(s2, m, 64);
  }
  float mu = s1 * (1.0f / 768.0f);
  float var = s2 * (1.0f / 768.0f) - mu * mu;
  float rs = rsqrtf(var + 1e-5f);

  float4 g0 = *(const float4*)(g + 8 * l);
  float4 g1 = *(const float4*)(g + 8 * l + 4);
  float4 g2 = *(const float4*)(g + 512 + 4 * l);
  float4 b0 = *(const float4*)(be + 8 * l);
  float4 b1 = *(const float4*)(be + 8 * l + 4);
  float4 b2 = *(const float4*)(be + 512 + 4 * l);

  float4 o0, o1, o2;
  o0.x = (v[0] - mu) * rs * g0.x + b0.x;
  o0.y = (v[1] - mu) * rs * g0.y + b0.y;
  o0.z = (v[2] - mu) * rs * g0.z + b0.z;
  o0.w = (v[3] - mu) * rs * g0.w + b0.w;
  o1.x = (v[4] - mu) * rs * g1.x + b1.x;
  o1.y = (v[5] - mu) * rs * g1.y + b1.y;
  o1.z = (v[6] - mu) * rs * g1.z + b1.z;
  o1.w = (v[7] - mu) * rs * g1.w + b1.w;
  o2.x = (v[8] - mu) * rs * g2.x + b2.x;
  o2.y = (v[9] - mu) * rs * g2.y + b2.y;
  o2.z = (v[10] - mu) * rs * g2.z + b2.z;
  o2.w = (v[11] - mu) * rs * g2.w + b2.w;

  float* orow = out + r * CH;
  *(float4*)(orow + 8 * l) = o0;
  *(float4*)(orow + 8 * l + 4) = o1;
  *(float4*)(orow + 512 + 4 * l) = o2;
}

// ---------------- launch ----------------
extern "C" void kernel_launch(void* const* d_in, const int* in_sizes, int n_in,
                              void* d_out, int out_size, void* d_ws, size_t ws_size,
                              hipStream_t stream) {
  (void)in_sizes; (void)n_in; (void)out_size; (void)ws_size;
  const float* x     = (const float*)d_in[0];
  const float* smask = (const float*)d_in[1];
  const float* wqkv  = (const float*)d_in[2];
  const float* bqkv  = (const float*)d_in[3];
  const float* wproj = (const float*)d_in[4];
  const float* bproj = (const float*)d_in[5];
  const float* table = (const float*)d_in[6];
  const float* lng   = (const float*)d_in[7];
  const float* lnb   = (const float*)d_in[8];
  const int*   rpi   = (const int*)d_in[9];
  float* out = (float*)d_out;

  char* ws = (char*)d_ws;
  bf16*  xb   = (bf16*)(ws);                      // 77,070,336 B
  bf16*  wqb  = (bf16*)(ws + 77070336);           //  3,538,944 B
  bf16*  wpb  = (bf16*)(ws + 80609280);           //  1,179,648 B
  float* comb = (float*)(ws + 81788928);          // 14,745,600 B
  bf16*  qkv  = (bf16*)(ws + 96534528);           // 231,211,008 B
  bf16*  aout = (bf16*)(ws + 327745536);          // 77,070,336 B
  bf16*  yb   = (bf16*)(ws + 96534528);           // aliases qkv (dead after attn)

  cvt_bf16<<<37632, 256, 0, stream>>>(x, xb, 9633792);
  cvt_bf16<<<1728, 256, 0, stream>>>(wqkv, wqb, 442368);
  cvt_bf16<<<576, 256, 0, stream>>>(wproj, wpb, 147456);
  build_comb<<<14400, 256, 0, stream>>>(table, rpi, smask, comb);
  qkv_gemm<<<dim3(392, 18), 256, 0, stream>>>(xb, wqb, bqkv, qkv);
  attn_kernel<<<dim3(1024, 6), 256, 0, stream>>>(qkv, comb, aout);
  proj_gemm<<<dim3(392, 6), 256, 0, stream>>>(aout, wpb, bproj, x, yb);
  ln_kernel<<<12544, 256, 0, stream>>>(yb, lng, lnb, out);
}